// Round 13
// baseline (339.359 us; speedup 1.0000x reference)
//
#include <hip/hip_runtime.h>
#include <hip/hip_bf16.h>

// BlurredNoise via MFMA implicit GEMM, round 21 = R20 at 4 waves/SIMD.
// R20 post-mortem: conflicts 0, clean dual-pipe (A=LDS, B=VMEM counted), yet
// MfmaUtil pinned ~25% and EVERY pipe at 20-30% of elapsed (MFMA 35k, LDS
// 30k, VMEM 36k of 132k cyc/CU) -> latency-bound with insufficient TLP at
// 2 waves/SIMD (both waves phase-aligned on the same waitcnts). All prior
// "TLP was null" results (R9/R15) were on shared-pipe-walled kernels.
// Fix (single variable): 8-wave blocks = 2 t-halves x 4-way k-split over
// the same 128t tile; grid 512 -> 2 blocks/CU x 8 waves = 16 waves/CU =
// 4/SIMD (VGPR 108<=128, LDS 2x49.3KB<=160KB, __launch_bounds__(512,4)).
// Quarters ts-balanced on the same region grid: kk0 W4x2+W3x1 (132ts),
// kk1 W3x2+W2x3 (144), kk2 W2x3+W1x5 (132), kk3 W1x11 (132).
// run_roll bodies byte-identical to R20 (verified). Reduction: 3 sequential
// accumulate rounds into kk0 via 32KB scratch in the dead x region.
// out[bc][F][t] = scale[F] * sum_j x[bc][t+j] * k[F][j]

#define KS      5000
#define IN_SEQ  9095
#define T_OUT   4096
#define NBC     16
#define NF      128
#define SWZSTEP 352               // B rows per tile (s>=313 all-zero via clamp)
#define FRONT   192               // x front zero pad (elements)
#define XPS2    9344              // bf16 copy row stride (elements)
#define CS      (NBC*XPS2)        // elems per global copy = 149,504
#define SWZ_BYTES (4*SWZSTEP*1024)    // 1,441,792
#define LSTRIDE 12320             // bytes per LDS x copy; /4=3080 == 8 mod 32
#define ACONST  10592             // 2*(KS-16+FRONT+120)

typedef __attribute__((ext_vector_type(8)))  short v8s;
typedef __attribute__((ext_vector_type(4)))  float v4f;
typedef __attribute__((ext_vector_type(16))) float v16f;

__device__ __forceinline__ unsigned short f2b(float v) {
  union { __hip_bfloat16 h; unsigned short u; } cv;
  cv.h = __float2bfloat16(v);   // RNE
  return cv.u;
}

// ---- fused pre-kernel: (a) filters -> 32x32x16 B-frags; (b) 4 shifted bf16
// x copies in GLOBAL: xb16[p][bc][i] = x_bc[i - FRONT + p], zeros outside ----
__global__ void build_pre(const float* __restrict__ filt,
                          const float* __restrict__ noise,
                          unsigned short* __restrict__ swz,
                          unsigned short* __restrict__ xb16) {
  const int b = blockIdx.x;
  if (b < 352) {                       // swz job: 4 tiles x 352 rows, 64 lanes/frag
    const int i = b * 256 + threadIdx.x;
    if (i >= 4 * SWZSTEP * 64) return;
    const int lane = i & 63;
    const int frag = i >> 6;
    const int ft = frag / SWZSTEP;
    const int s  = frag - ft * SWZSTEP;
    const int col = lane & 31;          // filter within tile
    const int hi  = lane >> 5;          // k-group (8 taps)
    const int jg0 = KS - 16 * (s + 1) + 8 * hi;
    const float* row = filt + (size_t)(ft * 32 + col) * KS;
    unsigned short o[8];
    #pragma unroll
    for (int j = 0; j < 8; ++j) {
      int jg = jg0 + j;
      int jc = jg < 0 ? 0 : jg;          // clamp ADDRESS, select VALUE
      float v = (jg >= 0 && jg < KS) ? row[jc] : 0.0f;
      o[j] = f2b(v);
    }
    *(uint4*)(swz + (((size_t)(ft * SWZSTEP + s)) << 9) + (lane << 3)) = *(uint4*)o;
  } else {                             // xb16 job: 4 copies x 16 rows x XPS2
    const int i = (b - 352) * 256 + threadIdx.x;
    if (i >= 4 * CS) return;
    const int p   = i / CS;
    const int rem = i - p * CS;
    const int r   = rem / XPS2;
    const int col = rem - r * XPS2;
    const int lg  = col - FRONT + p;
    const float v = (lg >= 0 && lg < IN_SEQ) ? noise[r * IN_SEQ + lg] : 0.0f;
    xb16[i] = f2b(v);
  }
}

// ---- one rolled region of the k-loop (byte-identical to R20) ----
// W: live 32-F tiles (tiles 4-W..3); D: B-prefetch depth (divides 12);
// sb0/iters RUNTIME. Per step: A ring prefetch dist 3 (2 m-streams, 2x
// ds_read_b64 each from the LDS x image), 2W MFMA, W B-refill dwordx4.
// All register indices compile-time (rule 20). No staging in the loop.
template<int W, int D>
__device__ __forceinline__ void run_roll(
    const char* __restrict__ swzg, const char* abase, int lane,
    int sb0, int iters, v16f (&acc)[2][4])
{
  v8s breg[D][W];
  v8s areg[4][2];                      // [ring slot][m-stream]

  const char* sp[W];
  #pragma unroll
  for (int w = 0; w < W; ++w)
    sp[w] = swzg + (((size_t)((4 - W + w) * SWZSTEP + sb0)) << 10) + 16 * lane;

  const char* ap = abase - 32 * sb0;   // LDS A byte ptr at region step 0

  // prologue: B depth D; A ring slots 0..2 = steps sb0..sb0+2
  #pragma unroll
  for (int d = 0; d < D; ++d)
    #pragma unroll
    for (int w = 0; w < W; ++w)
      breg[d][w] = *(const v8s*)(sp[w] + (d << 10));
  #pragma unroll
  for (int j = 0; j < 3; ++j)
    #pragma unroll
    for (int m = 0; m < 2; ++m) {
      *(uint2*)&areg[j][m]       = *(const uint2*)(ap - 32 * j + 64 * m);
      *((uint2*)&areg[j][m] + 1) = *(const uint2*)(ap - 32 * j + 64 * m + 8);
    }

  #pragma unroll 1
  for (int g = 0; g < iters; ++g) {
    #pragma unroll
    for (int ii = 0; ii < 12; ++ii) {
      // A prefetch for step ii+3 (region-tail reads stay inside the padded
      // image; values beyond the region are never consumed)
      #pragma unroll
      for (int m = 0; m < 2; ++m) {
        *(uint2*)&areg[(ii + 3) & 3][m] =
            *(const uint2*)(ap - 32 * (ii + 3) + 64 * m);
        *((uint2*)&areg[(ii + 3) & 3][m] + 1) =
            *(const uint2*)(ap - 32 * (ii + 3) + 64 * m + 8);
      }
      // MFMA: one A fragment per m-stream x W live B tiles (B shared)
      #pragma unroll
      for (int w = 0; w < W; ++w)
        #pragma unroll
        for (int m = 0; m < 2; ++m)
          acc[m][4 - W + w] = __builtin_amdgcn_mfma_f32_32x32x16_bf16(
              areg[ii & 3][m], breg[ii % D][w], acc[m][4 - W + w], 0, 0, 0);
      // B refill: slot ii%D <- step ii+D (tail over-reads: rows < SWZSTEP, dead)
      #pragma unroll
      for (int w = 0; w < W; ++w)
        breg[ii % D][w] = *(const v8s*)(sp[w] + ((ii + D) << 10));
    }
    #pragma unroll
    for (int w = 0; w < W; ++w) sp[w] += (12 << 10);
    ap -= 32 * 12;
  }
}

// ---- main kernel: 512 blocks x 512 threads ----
// wave w: th = w&1 (t-half of the 128t tile), kk = w>>1 (k quarter, 0..3).
__global__ __launch_bounds__(512, 4) void blur_mfma(
    const unsigned short* __restrict__ xb16,
    const unsigned short* __restrict__ swz,
    const float* __restrict__ scale,
    float* __restrict__ out)
{
  __shared__ __align__(16) char xb[4 * LSTRIDE];   // 49,280 B
  const int tid  = threadIdx.x;
  const int lane = tid & 63;
  const int wid  = tid >> 6;             // 0..7
  const int th   = wid & 1;
  const int kk   = wid >> 1;             // k quarter
  const int b  = blockIdx.x;
  const int bc = b >> 5;                 // 16 bc x 32 t-chunks of 128
  const int t0 = (b & 31) << 7;          // 128 output t per block
  const int row = lane & 31, hi = lane >> 5, p = row & 3;
  const char* swzg = (const char*)swz;

  // ---- prologue: 8 waves copy the 4 x-copies (wave = copy p, half) ----
  {
    const int cp   = wid & 3;
    const int half = wid >> 2;           // 6 chunks each
    const char* gsrc = (const char*)xb16 +
        2 * ((ptrdiff_t)cp * CS + (ptrdiff_t)bc * XPS2 + (t0 - 120)) +
        half * 6144;
    const char* gend = (const char*)xb16 + 2 * (ptrdiff_t)(4 * CS) - 16;
    char* ldst = xb + cp * LSTRIDE + half * 6144;
    uint4 tmp[6];
    #pragma unroll
    for (int j = 0; j < 6; ++j) {
      const char* s = gsrc + j * 1024 + 16 * lane;
      s = (s > gend) ? gend : s;         // tail clamp (values dead, addr safe)
      tmp[j] = *(const uint4*)s;
    }
    #pragma unroll
    for (int j = 0; j < 6; ++j)
      *(uint4*)(ldst + j * 1024 + 16 * lane) = tmp[j];
  }
  __syncthreads();

  // A base: copy p, byte = p*LSTRIDE + ACONST + 2(row-p) + 16hi + 128th
  // (+64 per m-stream, -32 per step; 8B-aligned since (row-p)%4==0)
  const char* abase = xb + p * LSTRIDE + ACONST + 2 * (row - p)
                         + 16 * hi + 128 * th;

  v16f acc[2][4];
  #pragma unroll
  for (int m = 0; m < 2; ++m)
    #pragma unroll
    for (int n = 0; n < 4; ++n)
      #pragma unroll
      for (int j = 0; j < 16; ++j) acc[m][n][j] = 0.0f;

  // k quarters (region grid: W4 s0..23, W3 24..59, W2 60..131, W1 132..323;
  // live ends: tile0 s<20, tile1 <49, tile2 <124, tile3 <313 -> zero-pad safe)
  if (kk == 0) {
    run_roll<4,  3>(swzg, abase, lane,   0,  2, acc);   // 96 ts
    run_roll<3,  4>(swzg, abase, lane,  24,  1, acc);   // 36 ts
  } else if (kk == 1) {
    run_roll<3,  4>(swzg, abase, lane,  36,  2, acc);   // 72 ts
    run_roll<2,  6>(swzg, abase, lane,  60,  3, acc);   // 72 ts
  } else if (kk == 2) {
    run_roll<2,  6>(swzg, abase, lane,  96,  3, acc);   // 72 ts
    run_roll<1, 12>(swzg, abase, lane, 132,  5, acc);   // 60 ts
  } else {
    run_roll<1, 12>(swzg, abase, lane, 192, 11, acc);   // 132 ts
  }

  // cross-wave reduction: 3 sequential accumulate rounds into kk0 per mm,
  // through 32KB scratch (th-disjoint 16KB) in the now-dead x region.
  __syncthreads();
  #pragma unroll
  for (int mm = 0; mm < 2; ++mm) {
    #pragma unroll
    for (int src = 1; src < 4; ++src) {
      if (kk == src) {
        #pragma unroll
        for (int n = 0; n < 4; ++n)
          #pragma unroll
          for (int r2 = 0; r2 < 4; ++r2) {
            v4f v = {acc[mm][n][4 * r2],     acc[mm][n][4 * r2 + 1],
                     acc[mm][n][4 * r2 + 2], acc[mm][n][4 * r2 + 3]};
            *(v4f*)(xb + th * 16384 + ((n * 4 + r2) << 10) + 16 * lane) = v;
          }
      }
      __syncthreads();
      if (kk == 0) {
        #pragma unroll
        for (int n = 0; n < 4; ++n)
          #pragma unroll
          for (int r2 = 0; r2 < 4; ++r2) {
            v4f v = *(const v4f*)(xb + th * 16384 + ((n * 4 + r2) << 10) + 16 * lane);
            acc[mm][n][4 * r2]     += v[0];
            acc[mm][n][4 * r2 + 1] += v[1];
            acc[mm][n][4 * r2 + 2] += v[2];
            acc[mm][n][4 * r2 + 3] += v[3];
          }
      }
      __syncthreads();                 // WAR guard before next writer
    }
  }

  // epilogue (kk0 waves, one per t-half): plain cached stores.
  // D col=lane&31 -> F, row=(reg&3)+8*(reg>>2)+4*hi -> t
  if (kk == 0) {
    #pragma unroll
    for (int m = 0; m < 2; ++m)
      #pragma unroll
      for (int n = 0; n < 4; ++n) {
        const int F = 32 * n + row;
        const float sc = scale[F];
        float* op = out + (size_t)(bc * NF + F) * T_OUT
                        + t0 + 64 * th + 32 * m + 4 * hi;
        #pragma unroll
        for (int r2 = 0; r2 < 4; ++r2) {
          v4f o = {acc[m][n][4 * r2] * sc, acc[m][n][4 * r2 + 1] * sc,
                   acc[m][n][4 * r2 + 2] * sc, acc[m][n][4 * r2 + 3] * sc};
          *(v4f*)(op + 8 * r2) = o;
        }
      }
  }
}

extern "C" void kernel_launch(void* const* d_in, const int* in_sizes, int n_in,
                              void* d_out, int out_size, void* d_ws, size_t ws_size,
                              hipStream_t stream) {
  const float* noise = (const float*)d_in[0];   // (2, 8, 9095) fp32
  const float* filt  = (const float*)d_in[1];   // (128, 5000) fp32
  const float* scale = (const float*)d_in[2];   // (1, 128, 1) fp32
  float* out = (float*)d_out;                   // (2, 1024, 4096) fp32

  unsigned short* swz  = (unsigned short*)d_ws;                      // 1.44 MB
  unsigned short* xb16 = (unsigned short*)((char*)d_ws + SWZ_BYTES); // 1.20 MB

  const int x_blocks = (4 * CS + 255) / 256;                // 2336
  build_pre<<<352 + x_blocks, 256, 0, stream>>>(filt, noise, swz, xb16);
  blur_mfma<<<512, 512, 0, stream>>>(xb16, swz, scale, out);
}

// Round 15
// 105.781 us; speedup vs baseline: 3.2081x; 3.2081x over previous
//
#include <hip/hip_runtime.h>
#include <hip/hip_bf16.h>

// BlurredNoise via MFMA implicit GEMM, round 24 = R22 with compile fix.
// R23 failed to compile: HIP uint2/uint4 are HIP_vector_type classes with no
// address_space(3) operator= -> cannot deref through as3 pointers. Fix: raw
// clang ext_vector ints (v2u/v4u) for all LDS accesses (plain vectors, no
// methods -> as3 loads/stores legal). Semantics identical to R22's design:
// (1) all LDS accesses via explicit address_space(3) pointers -> guaranteed
//     ds_read/ds_write; lgkmcnt decoupled from B's vmcnt stream (R20 suspect:
//     generic-pointer A-reads compiled to flat_load -> vmcnt-coupled with the
//     D-deep B prefetches -> ~600 cyc/step uniform stall).
// (2) A m-reuse: A(s,m=1) = A(s-2,m=0) (m offset 64B = 2 k-steps) -> one
//     6-slot single-stream ring, 2 ds_read_b64/step instead of 4.
// (3) T5 setprio(1/0) around the MFMA cluster.
// Base structure (R20, verified): 512x256, 2 t-halves x 2-way k-split over a
// 128t tile, whole-k x image in LDS loaded once from the global 4-shifted
// bf16 copy image, counted-vmcnt B register rotation, LDS reduction.
// out[bc][F][t] = scale[F] * sum_j x[bc][t+j] * k[F][j]

#define KS      5000
#define IN_SEQ  9095
#define T_OUT   4096
#define NBC     16
#define NF      128
#define SWZSTEP 352               // B rows per tile (s>=313 all-zero via clamp)
#define FRONT   192               // x front zero pad (elements)
#define XPS2    9344              // bf16 copy row stride (elements)
#define CS      (NBC*XPS2)        // elems per global copy = 149,504
#define SWZ_BYTES (4*SWZSTEP*1024)    // 1,441,792
#define LSTRIDE 12320             // bytes per LDS x copy; /4=3080 == 8 mod 32
#define ACONST  10592             // 2*(KS-16+FRONT+120)

typedef __attribute__((ext_vector_type(8)))  short v8s;
typedef __attribute__((ext_vector_type(4)))  float v4f;
typedef __attribute__((ext_vector_type(16))) float v16f;
typedef __attribute__((ext_vector_type(2)))  unsigned int v2u;
typedef __attribute__((ext_vector_type(4)))  unsigned int v4u;

// explicit LDS (address_space 3) pointer element types (raw ext_vectors only)
typedef __attribute__((address_space(3))) char       as3c;
typedef __attribute__((address_space(3))) const char as3cc;
typedef __attribute__((address_space(3))) const v2u  as3cv2u;
typedef __attribute__((address_space(3))) v4u        as3v4u;
typedef __attribute__((address_space(3))) v4f        as3v4f;
typedef __attribute__((address_space(3))) const v4f  as3cv4f;

__device__ __forceinline__ unsigned short f2b(float v) {
  union { __hip_bfloat16 h; unsigned short u; } cv;
  cv.h = __float2bfloat16(v);   // RNE
  return cv.u;
}

__device__ __forceinline__ v8s ldsA(const as3cc* p) {  // 16B via 2x ds_read_b64
  v8s r;
  *(v2u*)&r       = *(const as3cv2u*)(p);
  *((v2u*)&r + 1) = *(const as3cv2u*)(p + 8);
  return r;
}

// ---- fused pre-kernel: (a) filters -> 32x32x16 B-frags; (b) 4 shifted bf16
// x copies in GLOBAL: xb16[p][bc][i] = x_bc[i - FRONT + p], zeros outside ----
__global__ void build_pre(const float* __restrict__ filt,
                          const float* __restrict__ noise,
                          unsigned short* __restrict__ swz,
                          unsigned short* __restrict__ xb16) {
  const int b = blockIdx.x;
  if (b < 352) {                       // swz job: 4 tiles x 352 rows, 64 lanes/frag
    const int i = b * 256 + threadIdx.x;
    if (i >= 4 * SWZSTEP * 64) return;
    const int lane = i & 63;
    const int frag = i >> 6;
    const int ft = frag / SWZSTEP;
    const int s  = frag - ft * SWZSTEP;
    const int col = lane & 31;          // filter within tile
    const int hi  = lane >> 5;          // k-group (8 taps)
    const int jg0 = KS - 16 * (s + 1) + 8 * hi;
    const float* row = filt + (size_t)(ft * 32 + col) * KS;
    unsigned short o[8];
    #pragma unroll
    for (int j = 0; j < 8; ++j) {
      int jg = jg0 + j;
      int jc = jg < 0 ? 0 : jg;          // clamp ADDRESS, select VALUE
      float v = (jg >= 0 && jg < KS) ? row[jc] : 0.0f;
      o[j] = f2b(v);
    }
    *(v4u*)(swz + (((size_t)(ft * SWZSTEP + s)) << 9) + (lane << 3)) = *(v4u*)o;
  } else {                             // xb16 job: 4 copies x 16 rows x XPS2
    const int i = (b - 352) * 256 + threadIdx.x;
    if (i >= 4 * CS) return;
    const int p   = i / CS;
    const int rem = i - p * CS;
    const int r   = rem / XPS2;
    const int col = rem - r * XPS2;
    const int lg  = col - FRONT + p;
    const float v = (lg >= 0 && lg < IN_SEQ) ? noise[r * IN_SEQ + lg] : 0.0f;
    xb16[i] = f2b(v);
  }
}

// ---- one rolled region of the k-loop ----
// W: live 32-F tiles (tiles 4-W..3); D: B-prefetch depth (divides 12);
// sb0/iters RUNTIME. Per step: ONE A-frag ds prefetch (dist 3; m=1 reuses
// the frag of step-2 via the 6-slot ring), 2W MFMA under setprio, W B-refill
// dwordx4. All register indices compile-time (rule 20).
template<int W, int D>
__device__ __forceinline__ void run_roll(
    const char* __restrict__ swzg, const as3cc* axb, int lane,
    int sb0, int iters, v16f (&acc)[2][4])
{
  v8s breg[D][W];
  v8s areg[6];                         // ring: load (ii+3)%6; m0 ii%6, m1 (ii+4)%6

  const char* sp[W];
  #pragma unroll
  for (int w = 0; w < W; ++w)
    sp[w] = swzg + (((size_t)((4 - W + w) * SWZSTEP + sb0)) << 10) + 16 * lane;

  const as3cc* ap = axb - 32 * sb0;    // step-0 base for this region

  // prologue: B depth D; A ring abs steps -2..2 -> slots 4,5,0,1,2
  #pragma unroll
  for (int d = 0; d < D; ++d)
    #pragma unroll
    for (int w = 0; w < W; ++w)
      breg[d][w] = *(const v8s*)(sp[w] + (d << 10));
  {
    const as3cc* apP = ap - 64;        // anchor: offsets 32*(4-j) >= 0
    #pragma unroll
    for (int j = 0; j < 5; ++j)
      areg[(j + 4) % 6] = ldsA(apP + 32 * (4 - j));
  }

  #pragma unroll 1
  for (int g = 0; g < iters; ++g) {
    const as3cc* apb = ap - 32 * 14;   // anchor: prefetch offsets 32*(11-ii) >= 0
    #pragma unroll
    for (int ii = 0; ii < 12; ++ii) {
      // A prefetch for step ii+3 (single stream; region-tail reads stay
      // inside the padded image, values never consumed)
      areg[(ii + 3) % 6] = ldsA(apb + 32 * (11 - ii));
      // MFMA: m0 = frag(ii), m1 = frag(ii-2) (== m0 frag shifted +64B)
      __builtin_amdgcn_s_setprio(1);
      #pragma unroll
      for (int w = 0; w < W; ++w) {
        acc[0][4 - W + w] = __builtin_amdgcn_mfma_f32_32x32x16_bf16(
            areg[ii % 6],       breg[ii % D][w], acc[0][4 - W + w], 0, 0, 0);
        acc[1][4 - W + w] = __builtin_amdgcn_mfma_f32_32x32x16_bf16(
            areg[(ii + 4) % 6], breg[ii % D][w], acc[1][4 - W + w], 0, 0, 0);
      }
      __builtin_amdgcn_s_setprio(0);
      // B refill: slot ii%D <- step ii+D (tail over-reads: rows < SWZSTEP, dead)
      #pragma unroll
      for (int w = 0; w < W; ++w)
        breg[ii % D][w] = *(const v8s*)(sp[w] + ((ii + D) << 10));
    }
    #pragma unroll
    for (int w = 0; w < W; ++w) sp[w] += (12 << 10);
    ap -= 32 * 12;
  }
}

// ---- main kernel: 512 blocks x 256 threads ----
// wave w: th = w&1 (t-half of the 128t tile), kk = w>>1 (k-split half).
__global__ __launch_bounds__(256, 2) void blur_mfma(
    const unsigned short* __restrict__ xb16,
    const unsigned short* __restrict__ swz,
    const float* __restrict__ scale,
    float* __restrict__ out)
{
  __shared__ __align__(16) char xb[4 * LSTRIDE];   // 49,280 B
  as3c* xb3 = (as3c*)xb;                           // LDS-space view
  const int tid  = threadIdx.x;
  const int lane = tid & 63;
  const int wid  = tid >> 6;
  const int th   = wid & 1;
  const int kk   = wid >> 1;
  const int b  = blockIdx.x;
  const int bc = b >> 5;                 // 16 bc x 32 t-chunks of 128
  const int t0 = (b & 31) << 7;          // 128 output t per block
  const int row = lane & 31, hi = lane >> 5, p = row & 3;
  const char* swzg = (const char*)swz;

  // ---- prologue: copy wave wid's x copy (12 KB) global -> LDS, once ----
  {
    const char* gsrc = (const char*)xb16 +
        2 * ((ptrdiff_t)wid * CS + (ptrdiff_t)bc * XPS2 + (t0 - 120));
    const char* gend = (const char*)xb16 + 2 * (ptrdiff_t)(4 * CS) - 16;
    as3c* ldst = xb3 + wid * LSTRIDE;
    v4u tmp[12];
    #pragma unroll
    for (int j = 0; j < 12; ++j) {
      const char* s = gsrc + j * 1024 + 16 * lane;
      s = (s > gend) ? gend : s;         // tail clamp (values dead, addr safe)
      tmp[j] = *(const v4u*)s;
    }
    #pragma unroll
    for (int j = 0; j < 12; ++j)
      *(as3v4u*)(ldst + j * 1024 + 16 * lane) = tmp[j];
  }
  __syncthreads();

  // A base: copy p, byte = p*LSTRIDE + ACONST + 2(row-p) + 16hi + 128th
  // (m=1 handled by ring reuse: +64B == 2 steps; -32 per step)
  const as3cc* abase = (const as3cc*)xb3 + p * LSTRIDE + ACONST
                       + 2 * (row - p) + 16 * hi + 128 * th;

  v16f acc[2][4];
  #pragma unroll
  for (int m = 0; m < 2; ++m)
    #pragma unroll
    for (int n = 0; n < 4; ++n)
      #pragma unroll
      for (int j = 0; j < 16; ++j) acc[m][n][j] = 0.0f;

  // regions (live: W4 s<20, W3 <49, W2 <124, W1 <313; extras hit zero B rows)
  if (kk == 0) {
    run_roll<4,  3>(swzg, abase, lane,   0, 2, acc);   // s0..23
    run_roll<3,  4>(swzg, abase, lane,  24, 3, acc);   // s24..59
    run_roll<2,  6>(swzg, abase, lane,  60, 4, acc);   // s60..107
  } else {
    run_roll<2,  6>(swzg, abase, lane, 108, 2, acc);   // s108..131
    run_roll<1, 12>(swzg, abase, lane, 132, 16, acc);  // s132..323
  }

  // cross-wave reduction (per t-half pair): k1 waves write, k0 waves add.
  // Reuses the (now dead) x image LDS; th picks a disjoint 16KB region.
  __syncthreads();
  #pragma unroll
  for (int mm = 0; mm < 2; ++mm) {
    if (kk == 1) {
      #pragma unroll
      for (int n = 0; n < 4; ++n)
        #pragma unroll
        for (int r2 = 0; r2 < 4; ++r2) {
          v4f v = {acc[mm][n][4 * r2],     acc[mm][n][4 * r2 + 1],
                   acc[mm][n][4 * r2 + 2], acc[mm][n][4 * r2 + 3]};
          *(as3v4f*)(xb3 + th * 16384 + ((n * 4 + r2) << 10) + 16 * lane) = v;
        }
    }
    __syncthreads();
    if (kk == 0) {
      #pragma unroll
      for (int n = 0; n < 4; ++n)
        #pragma unroll
        for (int r2 = 0; r2 < 4; ++r2) {
          v4f v = *(const as3cv4f*)(xb3 + th * 16384 + ((n * 4 + r2) << 10) + 16 * lane);
          acc[mm][n][4 * r2]     += v[0];
          acc[mm][n][4 * r2 + 1] += v[1];
          acc[mm][n][4 * r2 + 2] += v[2];
          acc[mm][n][4 * r2 + 3] += v[3];
        }
    }
    __syncthreads();                   // WAR guard before next round's writes
  }

  // epilogue (k0 waves, one per t-half): plain cached stores.
  // D col=lane&31 -> F, row=(reg&3)+8*(reg>>2)+4*hi -> t
  if (kk == 0) {
    #pragma unroll
    for (int m = 0; m < 2; ++m)
      #pragma unroll
      for (int n = 0; n < 4; ++n) {
        const int F = 32 * n + row;
        const float sc = scale[F];
        float* op = out + (size_t)(bc * NF + F) * T_OUT
                        + t0 + 64 * th + 32 * m + 4 * hi;
        #pragma unroll
        for (int r2 = 0; r2 < 4; ++r2) {
          v4f o = {acc[m][n][4 * r2] * sc, acc[m][n][4 * r2 + 1] * sc,
                   acc[m][n][4 * r2 + 2] * sc, acc[m][n][4 * r2 + 3] * sc};
          *(v4f*)(op + 8 * r2) = o;
        }
      }
  }
}

extern "C" void kernel_launch(void* const* d_in, const int* in_sizes, int n_in,
                              void* d_out, int out_size, void* d_ws, size_t ws_size,
                              hipStream_t stream) {
  const float* noise = (const float*)d_in[0];   // (2, 8, 9095) fp32
  const float* filt  = (const float*)d_in[1];   // (128, 5000) fp32
  const float* scale = (const float*)d_in[2];   // (1, 128, 1) fp32
  float* out = (float*)d_out;                   // (2, 1024, 4096) fp32

  unsigned short* swz  = (unsigned short*)d_ws;                      // 1.44 MB
  unsigned short* xb16 = (unsigned short*)((char*)d_ws + SWZ_BYTES); // 1.20 MB

  const int x_blocks = (4 * CS + 255) / 256;                // 2336
  build_pre<<<352 + x_blocks, 256, 0, stream>>>(filt, noise, swz, xb16);
  blur_mfma<<<512, 256, 0, stream>>>(xb16, swz, scale, out);
}